// Round 2
// baseline (353.964 us; speedup 1.0000x reference)
//
#include <hip/hip_runtime.h>

#define NL 64  // NUM_LABELS == wave size

// Phase 1: per-LANE private LDS bins (no atomics in the hot loop).
// s_sum[label][lane]: lane i only touches column i -> bank = i%32, 2-way (free).
__global__ __launch_bounds__(64) void tl_reduce(const float* __restrict__ tex,
                                                const int* __restrict__ lab,
                                                float* __restrict__ g_sums,
                                                float* __restrict__ g_cnts,
                                                int n) {
    __shared__ float s_sum[NL][NL];  // 16 KB
    __shared__ float s_cnt[NL][NL];  // 16 KB
    const int lane = threadIdx.x;

    // zero bins: 1024 float4 per array, 16 iters/lane
    float4 z = make_float4(0.f, 0.f, 0.f, 0.f);
    float4* ps = (float4*)&s_sum[0][0];
    float4* pc = (float4*)&s_cnt[0][0];
    #pragma unroll
    for (int i = 0; i < (NL * NL / 4) / NL; ++i) {
        ps[i * NL + lane] = z;
        pc[i * NL + lane] = z;
    }
    __syncthreads();

    const int n4 = n >> 2;
    const float4* __restrict__ tex4 = (const float4*)tex;
    const int4* __restrict__ lab4 = (const int4*)lab;
    const int stride = gridDim.x * NL;

    // 1-deep software pipeline: next iteration's loads issue before the
    // current iteration's LDS read-modify-writes.
    int i = blockIdx.x * NL + lane;
    bool valid = i < n4;
    float4 t; int4 l;
    if (valid) { t = tex4[i]; l = lab4[i]; }
    while (valid) {
        const int inext = i + stride;
        const bool vnext = inext < n4;
        float4 tn; int4 ln;
        if (vnext) { tn = tex4[inext]; ln = lab4[inext]; }

        s_sum[l.x & (NL - 1)][lane] += t.x;  s_cnt[l.x & (NL - 1)][lane] += 1.0f;
        s_sum[l.y & (NL - 1)][lane] += t.y;  s_cnt[l.y & (NL - 1)][lane] += 1.0f;
        s_sum[l.z & (NL - 1)][lane] += t.z;  s_cnt[l.z & (NL - 1)][lane] += 1.0f;
        s_sum[l.w & (NL - 1)][lane] += t.w;  s_cnt[l.w & (NL - 1)][lane] += 1.0f;

        i = inext; valid = vnext; t = tn; l = ln;
    }

    // scalar tail (n % 4) handled by block 0 only
    if (blockIdx.x == 0) {
        const int base = n4 << 2;
        const int rem = n - base;
        if (lane < rem) {
            const int j = base + lane;
            s_sum[lab[j] & (NL - 1)][lane] += tex[j];
            s_cnt[lab[j] & (NL - 1)][lane] += 1.0f;
        }
    }
    __syncthreads();

    // Diagonal column-reduce: lane owns label==lane; reads s[lane][(k+lane)&63]
    // -> each bank hit by exactly 2 lanes per step (free).
    float s = 0.f, c = 0.f;
    #pragma unroll
    for (int k = 0; k < NL; ++k) {
        const int col = (k + lane) & (NL - 1);
        s += s_sum[lane][col];
        c += s_cnt[lane][col];
    }
    atomicAdd(&g_sums[lane], s);   // device-scope by default
    atomicAdd(&g_cnts[lane], c);
}

// Phase 2: build delta table in LDS (label 0 -> 0), apply out = tex - delta[lab].
__global__ __launch_bounds__(256) void tl_apply(const float* __restrict__ tex,
                                                const int* __restrict__ lab,
                                                const float* __restrict__ g_sums,
                                                const float* __restrict__ g_cnts,
                                                const float* __restrict__ intens,
                                                float* __restrict__ out, int n) {
    __shared__ float s_delta[NL];
    if (threadIdx.x < NL) {
        const int l = threadIdx.x;
        const float mean = g_sums[l] / fmaxf(g_cnts[l], 1.0f);
        s_delta[l] = (l > 0) ? (mean - intens[l]) : 0.0f;
    }
    __syncthreads();

    const int n4 = n >> 2;
    const int i = blockIdx.x * blockDim.x + threadIdx.x;
    if (i < n4) {
        const float4 t = ((const float4*)tex)[i];
        const int4 l = ((const int4*)lab)[i];
        float4 o;
        o.x = t.x - s_delta[l.x & (NL - 1)];
        o.y = t.y - s_delta[l.y & (NL - 1)];
        o.z = t.z - s_delta[l.z & (NL - 1)];
        o.w = t.w - s_delta[l.w & (NL - 1)];
        ((float4*)out)[i] = o;
    }
    if (blockIdx.x == 0) {
        const int base = n4 << 2;
        const int rem = n - base;
        if ((int)threadIdx.x < rem) {
            const int j = base + threadIdx.x;
            out[j] = tex[j] - s_delta[lab[j] & (NL - 1)];
        }
    }
}

extern "C" void kernel_launch(void* const* d_in, const int* in_sizes, int n_in,
                              void* d_out, int out_size, void* d_ws, size_t ws_size,
                              hipStream_t stream) {
    const float* tex    = (const float*)d_in[0];
    const int*   lab    = (const int*)d_in[1];
    const float* intens = (const float*)d_in[2];
    float* out = (float*)d_out;
    const int n = in_sizes[0];

    float* g_sums = (float*)d_ws;
    float* g_cnts = (float*)((char*)d_ws + NL * sizeof(float));

    // d_ws is re-poisoned to 0xAA before every timed launch — zero the bins.
    hipMemsetAsync(d_ws, 0, 2 * NL * sizeof(float), stream);

    // Phase 1: 1280 blocks x 64 threads (5 blocks/CU, LDS-limited at 32 KB).
    tl_reduce<<<1280, NL, 0, stream>>>(tex, lab, g_sums, g_cnts, n);

    // Phase 2: one float4 per thread.
    const int n4 = n >> 2;
    const int blocks = (n4 + 255) / 256;
    tl_apply<<<blocks, 256, 0, stream>>>(tex, lab, g_sums, g_cnts, intens, out, n);
}

// Round 3
// 337.960 us; speedup vs baseline: 1.0474x; 1.0474x over previous
//
#include <hip/hip_runtime.h>

#define NL 64  // NUM_LABELS

// Phase 1: per-column privatized bins updated with NO-RETURN LDS atomics
// (ds_add_f32 / ds_add_u32 -> no dependent read-modify-write chain).
// col = tid & 63: within a wave every lane has a distinct column -> no
// same-address collisions intra-wave; bank = col%32 -> 2-way (free).
// Counts packed two labels per u32 (u16 halves, max ~308 per half -> no carry).
__global__ __launch_bounds__(256) void tl_reduce(const float* __restrict__ tex,
                                                 const int* __restrict__ lab,
                                                 float* __restrict__ g_sums,
                                                 unsigned int* __restrict__ g_cnts,
                                                 int n) {
    __shared__ float s_sum[NL * NL];             // [label][col]      16 KB
    __shared__ unsigned int s_cnt[(NL / 2) * NL]; // [label>>1][col]   8 KB
    __shared__ float s_part[256];                 // per-quarter sums   1 KB
    __shared__ float c_part[256];                 // per-quarter counts 1 KB

    const int tid = threadIdx.x;
    const int col = tid & (NL - 1);

    for (int i = tid; i < NL * NL; i += 256) s_sum[i] = 0.0f;
    for (int i = tid; i < (NL / 2) * NL; i += 256) s_cnt[i] = 0u;
    __syncthreads();

    const int n4 = n >> 2;
    const float4* __restrict__ tex4 = (const float4*)tex;
    const int4* __restrict__ lab4 = (const int4*)lab;
    const int stride = gridDim.x * 256;

    int i = blockIdx.x * 256 + tid;
    bool v = i < n4;
    float4 t; int4 l;
    if (v) { t = tex4[i]; l = lab4[i]; }
    while (v) {
        const int inext = i + stride;
        const bool vn = inext < n4;
        float4 tn; int4 ln;
        if (vn) { tn = tex4[inext]; ln = lab4[inext]; }

        {
            const int lb = l.x & (NL - 1);
            atomicAdd(&s_sum[(lb << 6) | col], t.x);
            atomicAdd(&s_cnt[((lb >> 1) << 6) | col], 1u << ((lb & 1) << 4));
        }
        {
            const int lb = l.y & (NL - 1);
            atomicAdd(&s_sum[(lb << 6) | col], t.y);
            atomicAdd(&s_cnt[((lb >> 1) << 6) | col], 1u << ((lb & 1) << 4));
        }
        {
            const int lb = l.z & (NL - 1);
            atomicAdd(&s_sum[(lb << 6) | col], t.z);
            atomicAdd(&s_cnt[((lb >> 1) << 6) | col], 1u << ((lb & 1) << 4));
        }
        {
            const int lb = l.w & (NL - 1);
            atomicAdd(&s_sum[(lb << 6) | col], t.w);
            atomicAdd(&s_cnt[((lb >> 1) << 6) | col], 1u << ((lb & 1) << 4));
        }

        i = inext; v = vn; t = tn; l = ln;
    }

    // scalar tail (n % 4), block 0 only
    if (blockIdx.x == 0) {
        const int base = n4 << 2;
        const int rem = n - base;
        if (tid < rem) {
            const int j = base + tid;
            const int lb = lab[j] & (NL - 1);
            atomicAdd(&s_sum[(lb << 6) | col], tex[j]);
            atomicAdd(&s_cnt[((lb >> 1) << 6) | col], 1u << ((lb & 1) << 4));
        }
    }
    __syncthreads();

    // Block reduce: thread tid = (w<<6)|label sums 16 columns of its quarter w.
    {
        const int label = tid & (NL - 1);
        const int w = tid >> 6;
        float s = 0.0f;
        unsigned int c = 0u;
        const int sh = (label & 1) << 4;
        #pragma unroll
        for (int k = 0; k < 16; ++k) {
            const int cc = (w << 4) | ((k + tid) & 15);
            s += s_sum[(label << 6) | cc];
            c += (s_cnt[((label >> 1) << 6) | cc] >> sh) & 0xffffu;
        }
        s_part[tid] = s;
        c_part[tid] = (float)c;
    }
    __syncthreads();

    if (tid < NL) {
        const float ss = s_part[tid] + s_part[64 + tid] + s_part[128 + tid] + s_part[192 + tid];
        const float cc = c_part[tid] + c_part[64 + tid] + c_part[128 + tid] + c_part[192 + tid];
        atomicAdd(&g_sums[tid], ss);
        atomicAdd(&g_cnts[tid], (unsigned int)cc);
    }
}

// Phase 2: build delta table in LDS (label 0 -> 0), apply out = tex - delta[lab].
__global__ __launch_bounds__(256) void tl_apply(const float* __restrict__ tex,
                                                const int* __restrict__ lab,
                                                const float* __restrict__ g_sums,
                                                const unsigned int* __restrict__ g_cnts,
                                                const float* __restrict__ intens,
                                                float* __restrict__ out, int n) {
    __shared__ float s_delta[NL];
    if (threadIdx.x < NL) {
        const int l = threadIdx.x;
        const float mean = g_sums[l] / fmaxf((float)g_cnts[l], 1.0f);
        s_delta[l] = (l > 0) ? (mean - intens[l]) : 0.0f;
    }
    __syncthreads();

    const int n4 = n >> 2;
    const int i = blockIdx.x * blockDim.x + threadIdx.x;
    if (i < n4) {
        const float4 t = ((const float4*)tex)[i];
        const int4 l = ((const int4*)lab)[i];
        float4 o;
        o.x = t.x - s_delta[l.x & (NL - 1)];
        o.y = t.y - s_delta[l.y & (NL - 1)];
        o.z = t.z - s_delta[l.z & (NL - 1)];
        o.w = t.w - s_delta[l.w & (NL - 1)];
        ((float4*)out)[i] = o;
    }
    if (blockIdx.x == 0) {
        const int base = n4 << 2;
        const int rem = n - base;
        if ((int)threadIdx.x < rem) {
            const int j = base + threadIdx.x;
            out[j] = tex[j] - s_delta[lab[j] & (NL - 1)];
        }
    }
}

extern "C" void kernel_launch(void* const* d_in, const int* in_sizes, int n_in,
                              void* d_out, int out_size, void* d_ws, size_t ws_size,
                              hipStream_t stream) {
    const float* tex    = (const float*)d_in[0];
    const int*   lab    = (const int*)d_in[1];
    const float* intens = (const float*)d_in[2];
    float* out = (float*)d_out;
    const int n = in_sizes[0];

    float* g_sums = (float*)d_ws;
    unsigned int* g_cnts = (unsigned int*)((char*)d_ws + NL * sizeof(float));

    // d_ws is re-poisoned to 0xAA before every timed launch — zero the bins.
    hipMemsetAsync(d_ws, 0, 2 * NL * sizeof(float), stream);

    // Phase 1: 1536 blocks x 256 threads (6 blocks/CU at 26 KB LDS, 24 waves/CU).
    tl_reduce<<<1536, 256, 0, stream>>>(tex, lab, g_sums, g_cnts, n);

    // Phase 2: one float4 per thread.
    const int n4 = n >> 2;
    const int blocks = (n4 + 255) / 256;
    tl_apply<<<blocks, 256, 0, stream>>>(tex, lab, g_sums, g_cnts, intens, out, n);
}